// Round 1
// baseline (232.057 us; speedup 1.0000x reference)
//
#include <hip/hip_runtime.h>
#include <hip/hip_bf16.h>

// ---------- types ----------
typedef short bf16x8 __attribute__((ext_vector_type(8)));
typedef float f32x4 __attribute__((ext_vector_type(4)));

#define NB 4
#define C 256
#define HW 4096
#define NROWS (NB * HW)   // 16384
#define EPSF 1e-5f

// ---------- helpers ----------
__device__ __forceinline__ unsigned short f2bf(float f) {
    unsigned int u = __float_as_uint(f);
    unsigned int r = u + 0x7fffu + ((u >> 16) & 1u);
    return (unsigned short)(r >> 16);
}
__device__ __forceinline__ float bf2f(unsigned int h) {
    return __uint_as_float(h << 16);
}
__device__ __forceinline__ void unpack8(uint4 u, float* v) {
    unsigned int w0 = u.x, w1 = u.y, w2 = u.z, w3 = u.w;
    v[0] = bf2f(w0 & 0xffffu); v[1] = bf2f(w0 >> 16);
    v[2] = bf2f(w1 & 0xffffu); v[3] = bf2f(w1 >> 16);
    v[4] = bf2f(w2 & 0xffffu); v[5] = bf2f(w2 >> 16);
    v[6] = bf2f(w3 & 0xffffu); v[7] = bf2f(w3 >> 16);
}
__device__ __forceinline__ float waveReduceSum(float v) {
    for (int off = 32; off > 0; off >>= 1) v += __shfl_xor(v, off);
    return v;
}
__device__ __forceinline__ float waveReduceMax(float v) {
    for (int off = 32; off > 0; off >>= 1) v = fmaxf(v, __shfl_xor(v, off));
    return v;
}

// ---------- K1: per-channel mean of y ----------
__global__ __launch_bounds__(256) void mu_kernel(const float* __restrict__ y,
                                                 float* __restrict__ mu) {
    int c = blockIdx.x;
    int tid = threadIdx.x;
    float s = 0.f;
    const float* base = y + (size_t)c * HW;
    for (int n = 0; n < NB; n++) {
        const float* bn = base + (size_t)n * C * HW;
        for (int i = tid; i < HW; i += 256) s += bn[i];
    }
    s = waveReduceSum(s);
    __shared__ float red[4];
    int lane = tid & 63, wave = tid >> 6;
    if (lane == 0) red[wave] = s;
    __syncthreads();
    if (tid == 0) mu[c] = (red[0] + red[1] + red[2] + red[3]) * (1.0f / 16384.0f);
}

// ---------- K2: center, L2-normalize over C, transpose to (n,p,c) bf16 ----------
#define TP 32
#define TSTRIDE 257
__global__ __launch_bounds__(256) void prep_kernel(const float* __restrict__ x,
                                                   const float* __restrict__ y,
                                                   const float* __restrict__ mu,
                                                   unsigned short* __restrict__ Xn,
                                                   unsigned short* __restrict__ Yn) {
    __shared__ float smu[C];
    __shared__ float tile[TP * TSTRIDE];
    __shared__ float red[8 * 32];
    __shared__ float invn[TP];
    int tid = threadIdx.x;
    smu[tid] = mu[tid];
    int blk = blockIdx.x;
    int n = blk >> 7;                // 128 blocks per batch
    int p0 = (blk & 127) * TP;
    int tp = tid & 31, cc = tid >> 5;
    __syncthreads();
    for (int pass = 0; pass < 2; pass++) {
        const float* in = pass ? y : x;
        unsigned short* out = pass ? Yn : Xn;
        const float* base = in + (size_t)n * C * HW + p0 + tp;
        float ssq = 0.f;
        for (int c = cc; c < C; c += 8) {
            float v = base[(size_t)c * HW] - smu[c];
            tile[tp * TSTRIDE + c] = v;
            ssq += v * v;
        }
        red[cc * 32 + tp] = ssq;
        __syncthreads();
        if (tid < 32) {
            float s = 0.f;
            for (int k = 0; k < 8; k++) s += red[k * 32 + tid];
            invn[tid] = rsqrtf(s);
        }
        __syncthreads();
        int c2 = (tid & 127) * 2;
        int pp = tid >> 7;
        for (int p = pp; p < TP; p += 2) {
            float inv = invn[p];
            unsigned short b0 = f2bf(tile[p * TSTRIDE + c2] * inv);
            unsigned short b1 = f2bf(tile[p * TSTRIDE + c2 + 1] * inv);
            unsigned int pack = (unsigned int)b0 | ((unsigned int)b1 << 16);
            ((unsigned int*)out)[(size_t)(n * HW + p0 + p) * (C / 2) + (c2 >> 1)] = pack;
        }
        __syncthreads();
    }
}

// ---------- K3: batched GEMM cos = Xn * Yn^T, bf16 out ----------
#define BM 128
#define BN 128
#define BK 32
#define LSTRIDE 40   // bf16 elems per LDS row (80B: 16B aligned, conflict-light)
__global__ __launch_bounds__(256) void gemm_cos(const unsigned short* __restrict__ Xn,
                                                const unsigned short* __restrict__ Yn,
                                                unsigned short* __restrict__ Cos) {
    int n = blockIdx.z;
    int pBase = blockIdx.y * BM;
    int qBase = blockIdx.x * BN;
    const unsigned short* A = Xn + (size_t)n * HW * C;
    const unsigned short* B = Yn + (size_t)n * HW * C;
    __shared__ unsigned short sA[BM * LSTRIDE];
    __shared__ unsigned short sB[BN * LSTRIDE];
    int tid = threadIdx.x;
    int lane = tid & 63;
    int wave = tid >> 6;
    int wm = (wave >> 1) * 64;
    int wn = (wave & 1) * 64;
    f32x4 acc[4][4];
#pragma unroll
    for (int i = 0; i < 4; i++)
#pragma unroll
        for (int j = 0; j < 4; j++) acc[i][j] = (f32x4){0.f, 0.f, 0.f, 0.f};

    int lrow = tid >> 2;           // 0..63
    int lcol = (tid & 3) * 8;      // 0,8,16,24
    int mrow = lane & 15;
    int koff = (lane >> 4) * 8;

#pragma unroll
    for (int k0 = 0; k0 < C; k0 += BK) {
        uint4 a0 = *(const uint4*)(A + (size_t)(pBase + lrow) * C + k0 + lcol);
        uint4 a1 = *(const uint4*)(A + (size_t)(pBase + lrow + 64) * C + k0 + lcol);
        uint4 b0 = *(const uint4*)(B + (size_t)(qBase + lrow) * C + k0 + lcol);
        uint4 b1 = *(const uint4*)(B + (size_t)(qBase + lrow + 64) * C + k0 + lcol);
        __syncthreads();
        *(uint4*)&sA[lrow * LSTRIDE + lcol] = a0;
        *(uint4*)&sA[(lrow + 64) * LSTRIDE + lcol] = a1;
        *(uint4*)&sB[lrow * LSTRIDE + lcol] = b0;
        *(uint4*)&sB[(lrow + 64) * LSTRIDE + lcol] = b1;
        __syncthreads();
        bf16x8 af[4], bfr[4];
#pragma unroll
        for (int i = 0; i < 4; i++)
            af[i] = *(const bf16x8*)&sA[(wm + i * 16 + mrow) * LSTRIDE + koff];
#pragma unroll
        for (int j = 0; j < 4; j++)
            bfr[j] = *(const bf16x8*)&sB[(wn + j * 16 + mrow) * LSTRIDE + koff];
#pragma unroll
        for (int i = 0; i < 4; i++)
#pragma unroll
            for (int j = 0; j < 4; j++)
                acc[i][j] = __builtin_amdgcn_mfma_f32_16x16x32_bf16(af[i], bfr[j], acc[i][j], 0, 0, 0);
    }

    // epilogue: C/D layout col=lane&15, row=(lane>>4)*4+reg
    int col = lane & 15;
    int rquad = (lane >> 4) * 4;
    unsigned short* Crow = Cos + (size_t)n * HW * HW;
#pragma unroll
    for (int i = 0; i < 4; i++) {
#pragma unroll
        for (int j = 0; j < 4; j++) {
#pragma unroll
            for (int r = 0; r < 4; r++) {
                int p = pBase + wm + i * 16 + rquad + r;
                int q = qBase + wn + j * 16 + col;
                Crow[(size_t)p * HW + q] = f2bf(acc[i][j][r]);
            }
        }
    }
}

// ---------- K4: per-row max + exp-sum -> alpha, beta ----------
__global__ __launch_bounds__(256) void row_stats(const unsigned short* __restrict__ Cos,
                                                 float* __restrict__ alphaArr,
                                                 float* __restrict__ betaArr) {
    size_t row = blockIdx.x;   // 0..16383 (n*4096+p)
    int tid = threadIdx.x;
    const uint4* rp = (const uint4*)(Cos + row * HW);
    uint4 u0 = rp[tid * 2];
    uint4 u1 = rp[tid * 2 + 1];
    float v[16];
    unpack8(u0, v);
    unpack8(u1, v + 8);
    float mx = v[0];
#pragma unroll
    for (int k = 1; k < 16; k++) mx = fmaxf(mx, v[k]);
    mx = waveReduceMax(mx);
    __shared__ float redm[4];
    __shared__ float reds[4];
    int lane = tid & 63, wave = tid >> 6;
    if (lane == 0) redm[wave] = mx;
    __syncthreads();
    float M = fmaxf(fmaxf(redm[0], redm[1]), fmaxf(redm[2], redm[3]));
    float m = (1.0f - M) + EPSF;
    float alpha = 2.0f / m;
    float base = 2.0f - alpha;
    float s = 0.f;
#pragma unroll
    for (int k = 0; k < 16; k++) s += __expf(base + alpha * v[k]);
    s = waveReduceSum(s);
    if (lane == 0) reds[wave] = s;
    __syncthreads();
    if (tid == 0) {
        float S = reds[0] + reds[1] + reds[2] + reds[3];
        alphaArr[row] = alpha;
        betaArr[row] = base - __logf(S);
    }
}

// ---------- K5a: column-wise logit max over p-chunk ----------
#define PCH 32
#define PCHUNKS (HW / PCH)   // 128
__global__ __launch_bounds__(256) void col_partial(const unsigned short* __restrict__ Cos,
                                                   const float* __restrict__ alphaArr,
                                                   const float* __restrict__ betaArr,
                                                   float* __restrict__ partial) {
    int n = blockIdx.z;
    int q0 = blockIdx.y * 2048;
    int pc = blockIdx.x;    // 0..127
    int tid = threadIdx.x;
    int qoff = q0 + tid * 8;
    const unsigned short* base = Cos + (size_t)n * HW * HW;
    float mx[8];
#pragma unroll
    for (int k = 0; k < 8; k++) mx[k] = -1e30f;
    int prow0 = pc * PCH;
    for (int pp = 0; pp < PCH; pp++) {
        int p = prow0 + pp;
        size_t grow = (size_t)n * HW + p;
        float alpha = alphaArr[grow];
        float beta = betaArr[grow];
        uint4 u = *(const uint4*)(base + (size_t)p * HW + qoff);
        float cv[8];
        unpack8(u, cv);
#pragma unroll
        for (int k = 0; k < 8; k++) mx[k] = fmaxf(mx[k], alpha * cv[k] + beta);
    }
    float* outp = partial + ((size_t)(n * PCHUNKS + pc)) * HW + qoff;
#pragma unroll
    for (int k = 0; k < 8; k++) outp[k] = mx[k];
}

// ---------- K5b: reduce over p-chunks, exp, sum over q ----------
__global__ __launch_bounds__(256) void col_reduce(const float* __restrict__ partial,
                                                  float* __restrict__ cxsum) {
    int n = blockIdx.y;
    int q = blockIdx.x * 256 + threadIdx.x;
    const float* p = partial + (size_t)n * PCHUNKS * HW + q;
    float mx = -1e30f;
#pragma unroll 4
    for (int c = 0; c < PCHUNKS; c++) mx = fmaxf(mx, p[(size_t)c * HW]);
    float val = __expf(mx);
    val = waveReduceSum(val);
    __shared__ float red[4];
    int lane = threadIdx.x & 63, wave = threadIdx.x >> 6;
    if (lane == 0) red[wave] = val;
    __syncthreads();
    if (threadIdx.x == 0)
        atomicAdd(&cxsum[n], red[0] + red[1] + red[2] + red[3]);
}

// ---------- K6: final loss ----------
__global__ void finalize(const float* __restrict__ cxsum, float* __restrict__ out) {
    if (threadIdx.x == 0 && blockIdx.x == 0) {
        float loss = 0.f;
        for (int n = 0; n < NB; n++) {
            float cx = cxsum[n] * (1.0f / 4096.0f);
            loss += -logf(cx + EPSF);
        }
        out[0] = loss * 0.25f;
    }
}

// ---------- launch ----------
extern "C" void kernel_launch(void* const* d_in, const int* in_sizes, int n_in,
                              void* d_out, int out_size, void* d_ws, size_t ws_size,
                              hipStream_t stream) {
    const float* x = (const float*)d_in[0];
    const float* y = (const float*)d_in[1];
    float* out = (float*)d_out;
    char* ws = (char*)d_ws;

    // workspace layout (total ~152.3 MiB)
    float* mu            = (float*)(ws + 0);                         // 1 KiB
    float* alphaArr      = (float*)(ws + 1024);                      // 64 KiB
    float* betaArr       = (float*)(ws + 1024 + 65536);              // 64 KiB
    float* cxsum         = (float*)(ws + 1024 + 2 * 65536);          // 16 B
    unsigned short* Xn   = (unsigned short*)(ws + 262144);           // 8 MiB
    unsigned short* Yn   = (unsigned short*)(ws + 262144 + 8388608); // 8 MiB
    float* partial       = (float*)(ws + 262144 + 2 * 8388608);      // 8 MiB
    unsigned short* Cos  = (unsigned short*)(ws + 262144 + 3 * 8388608); // 128 MiB

    hipMemsetAsync(cxsum, 0, NB * sizeof(float), stream);

    mu_kernel<<<C, 256, 0, stream>>>(y, mu);
    prep_kernel<<<NROWS / TP, 256, 0, stream>>>(x, y, mu, Xn, Yn);
    gemm_cos<<<dim3(HW / BN, HW / BM, NB), 256, 0, stream>>>(Xn, Yn, Cos);
    row_stats<<<NROWS, 256, 0, stream>>>(Cos, alphaArr, betaArr);
    col_partial<<<dim3(PCHUNKS, 2, NB), 256, 0, stream>>>(Cos, alphaArr, betaArr, partial);
    col_reduce<<<dim3(HW / 256, NB), 256, 0, stream>>>(partial, cxsum);
    finalize<<<1, 64, 0, stream>>>(cxsum, out);
}

// Round 2
// 229.953 us; speedup vs baseline: 1.0092x; 1.0092x over previous
//
#include <hip/hip_runtime.h>
#include <hip/hip_bf16.h>

// ---------- types ----------
typedef short bf16x8 __attribute__((ext_vector_type(8)));
typedef float f32x4 __attribute__((ext_vector_type(4)));

#define NB 4
#define C 256
#define HW 4096
#define NROWS (NB * HW)   // 16384
#define EPSF 1e-5f

// ---------- helpers ----------
__device__ __forceinline__ unsigned short f2bf(float f) {
    unsigned int u = __float_as_uint(f);
    unsigned int r = u + 0x7fffu + ((u >> 16) & 1u);
    return (unsigned short)(r >> 16);
}
__device__ __forceinline__ float bf2f(unsigned int h) {
    return __uint_as_float(h << 16);
}
__device__ __forceinline__ void unpack8(uint4 u, float* v) {
    unsigned int w0 = u.x, w1 = u.y, w2 = u.z, w3 = u.w;
    v[0] = bf2f(w0 & 0xffffu); v[1] = bf2f(w0 >> 16);
    v[2] = bf2f(w1 & 0xffffu); v[3] = bf2f(w1 >> 16);
    v[4] = bf2f(w2 & 0xffffu); v[5] = bf2f(w2 >> 16);
    v[6] = bf2f(w3 & 0xffffu); v[7] = bf2f(w3 >> 16);
}
__device__ __forceinline__ float waveReduceSum(float v) {
    for (int off = 32; off > 0; off >>= 1) v += __shfl_xor(v, off);
    return v;
}
__device__ __forceinline__ float waveReduceMax(float v) {
    for (int off = 32; off > 0; off >>= 1) v = fmaxf(v, __shfl_xor(v, off));
    return v;
}
// async global->LDS 16B copy; lds ptr must be wave-uniform-base + lane*16
typedef __attribute__((address_space(1))) const unsigned int glb_cu;
typedef __attribute__((address_space(3))) unsigned int lds_u;
__device__ __forceinline__ void async_copy16(const unsigned short* g, unsigned short* l) {
    __builtin_amdgcn_global_load_lds((glb_cu*)g, (lds_u*)l, 16, 0, 0);
}

// ---------- K1: per-channel mean of y ----------
__global__ __launch_bounds__(256) void mu_kernel(const float* __restrict__ y,
                                                 float* __restrict__ mu) {
    int c = blockIdx.x;
    int tid = threadIdx.x;
    float s = 0.f;
    const float* base = y + (size_t)c * HW;
    for (int n = 0; n < NB; n++) {
        const float* bn = base + (size_t)n * C * HW;
        for (int i = tid; i < HW; i += 256) s += bn[i];
    }
    s = waveReduceSum(s);
    __shared__ float red[4];
    int lane = tid & 63, wave = tid >> 6;
    if (lane == 0) red[wave] = s;
    __syncthreads();
    if (tid == 0) mu[c] = (red[0] + red[1] + red[2] + red[3]) * (1.0f / 16384.0f);
}

// ---------- K2: center, L2-normalize over C, transpose to (n,p,c) bf16 ----------
#define TP 32
#define TSTRIDE 257
__global__ __launch_bounds__(256) void prep_kernel(const float* __restrict__ x,
                                                   const float* __restrict__ y,
                                                   const float* __restrict__ mu,
                                                   unsigned short* __restrict__ Xn,
                                                   unsigned short* __restrict__ Yn) {
    __shared__ float smu[C];
    __shared__ float tile[TP * TSTRIDE];
    __shared__ float red[8 * 32];
    __shared__ float invn[TP];
    int tid = threadIdx.x;
    smu[tid] = mu[tid];
    int blk = blockIdx.x;
    int n = blk >> 7;                // 128 blocks per batch
    int p0 = (blk & 127) * TP;
    int tp = tid & 31, cc = tid >> 5;
    __syncthreads();
    for (int pass = 0; pass < 2; pass++) {
        const float* in = pass ? y : x;
        unsigned short* out = pass ? Yn : Xn;
        const float* base = in + (size_t)n * C * HW + p0 + tp;
        float ssq = 0.f;
        for (int c = cc; c < C; c += 8) {
            float v = base[(size_t)c * HW] - smu[c];
            tile[tp * TSTRIDE + c] = v;
            ssq += v * v;
        }
        red[cc * 32 + tp] = ssq;
        __syncthreads();
        if (tid < 32) {
            float s = 0.f;
            for (int k = 0; k < 8; k++) s += red[k * 32 + tid];
            invn[tid] = rsqrtf(s);
        }
        __syncthreads();
        int c2 = (tid & 127) * 2;
        int pp = tid >> 7;
        for (int p = pp; p < TP; p += 2) {
            float inv = invn[p];
            unsigned short b0 = f2bf(tile[p * TSTRIDE + c2] * inv);
            unsigned short b1 = f2bf(tile[p * TSTRIDE + c2 + 1] * inv);
            unsigned int pack = (unsigned int)b0 | ((unsigned int)b1 << 16);
            ((unsigned int*)out)[(size_t)(n * HW + p0 + p) * (C / 2) + (c2 >> 1)] = pack;
        }
        __syncthreads();
    }
}

// ---------- K3: batched GEMM cos = Xn * Yn^T, bf16 out ----------
// 128x128 tile, K=256 in two halves of 128. global_load_lds staging into
// XOR-swizzled LDS (16B chunks: chunk' = chunk ^ (row&15)) -> conflict-optimal
// ds_read_b128 AND async-copy compatible (no padding). 64KB LDS -> 2 blocks/CU
// so staging of one block overlaps compute of the other. Epilogue transposes
// through LDS (bf16, stride 136) for coalesced dwordx4 stores.
#define EPSTRIDE 136
__global__ __launch_bounds__(256, 2) void gemm_cos(const unsigned short* __restrict__ Xn,
                                                   const unsigned short* __restrict__ Yn,
                                                   unsigned short* __restrict__ Cos) {
    __shared__ unsigned short lds_us[32768];   // 64 KB: A[16K ushorts] B[16K]
    int n = blockIdx.z;
    int pBase = blockIdx.y * 128, qBase = blockIdx.x * 128;
    const unsigned short* Ab = Xn + ((size_t)n * HW + pBase) * C;
    const unsigned short* Bb = Yn + ((size_t)n * HW + qBase) * C;
    int tid = threadIdx.x, lane = tid & 63, wave = tid >> 6;
    int wm = (wave >> 1) * 64, wn = (wave & 1) * 64;
    int mrow = lane & 15, quad = lane >> 4;

    f32x4 acc[4][4];
#pragma unroll
    for (int i = 0; i < 4; i++)
#pragma unroll
        for (int j = 0; j < 4; j++) acc[i][j] = (f32x4){0.f, 0.f, 0.f, 0.f};

#pragma unroll
    for (int h = 0; h < 2; h++) {
        // stage half h: 128 rows x 16 chunks(16B) per matrix, swizzled
#pragma unroll
        for (int mat = 0; mat < 2; mat++) {
            const unsigned short* g = mat ? Bb : Ab;
            unsigned short* lbase = lds_us + mat * 16384;
#pragma unroll
            for (int t = 0; t < 8; t++) {
                int slot = t * 256 + tid;           // 0..2047
                int r = slot >> 4, cl = slot & 15;
                int c = h * 16 + (cl ^ (r & 15));   // global 16B-chunk index
                async_copy16(g + (size_t)r * C + c * 8, lbase + slot * 8);
            }
        }
        __syncthreads();   // drains vmcnt -> staged data visible
#pragma unroll
        for (int kkl = 0; kkl < 4; kkl++) {
            int cl4 = kkl * 4 + quad;
            int clp = cl4 ^ mrow;
            bf16x8 af[4], bfr[4];
#pragma unroll
            for (int i = 0; i < 4; i++) {
                af[i]  = *(const bf16x8*)(lds_us + (wm + i * 16 + mrow) * 128 + clp * 8);
                bfr[i] = *(const bf16x8*)(lds_us + 16384 + (wn + i * 16 + mrow) * 128 + clp * 8);
            }
#pragma unroll
            for (int i = 0; i < 4; i++)
#pragma unroll
                for (int j = 0; j < 4; j++)
                    acc[i][j] = __builtin_amdgcn_mfma_f32_16x16x32_bf16(af[i], bfr[j], acc[i][j], 0, 0, 0);
        }
        __syncthreads();   // before restaging / epilogue reuse
    }

    // ---- epilogue: transpose through LDS (bf16), coalesced dwordx4 stores ----
    unsigned short* epb = lds_us;  // 128 x EPSTRIDE bf16 = 34 KB
    int col = lane & 15, quad4 = quad * 4;
#pragma unroll
    for (int i = 0; i < 4; i++)
#pragma unroll
        for (int j = 0; j < 4; j++)
#pragma unroll
            for (int r = 0; r < 4; r++)
                epb[(wm + i * 16 + quad4 + r) * EPSTRIDE + wn + j * 16 + col] = f2bf(acc[i][j][r]);
    __syncthreads();
    unsigned short* Crow = Cos + (size_t)n * HW * HW;
#pragma unroll
    for (int it = 0; it < 8; it++) {
        int e = it * 2048 + tid * 8;
        int r = e >> 7, cg = e & 127;
        uint4 o = *(const uint4*)(epb + r * EPSTRIDE + cg);
        *(uint4*)(Crow + (size_t)(pBase + r) * HW + qBase + cg) = o;
    }
}

// ---------- K4: fused per-row stats + column logit-max (reads Cos ONCE) ----------
// block = 16 full rows; data register-resident (16 rows x 16 q x bf16 / thread).
// logit l_pq = alpha_p*cos + base_p - log(S_p); column max in logit space.
__global__ __launch_bounds__(256, 2) void rowcol(const unsigned short* __restrict__ Cos,
                                                 float* __restrict__ partial) {
    int n = blockIdx.y, chunk = blockIdx.x;   // chunk: 0..255 (16 rows each)
    int tid = threadIdx.x, lane = tid & 63, wave = tid >> 6;
    const unsigned short* base = Cos + ((size_t)n * HW + chunk * 16) * HW + tid * 16;
    uint4 d[16][2];
#pragma unroll
    for (int r = 0; r < 16; r++) {
        d[r][0] = *(const uint4*)(base + (size_t)r * HW);
        d[r][1] = *(const uint4*)(base + (size_t)r * HW + 8);
    }
    __shared__ float redm[16 * 4];
    __shared__ float salpha[16], sbase[16], sbeta[16];

    // pass 1: row max -> alpha
#pragma unroll
    for (int r = 0; r < 16; r++) {
        float v[16];
        unpack8(d[r][0], v); unpack8(d[r][1], v + 8);
        float m = v[0];
#pragma unroll
        for (int k = 1; k < 16; k++) m = fmaxf(m, v[k]);
        m = waveReduceMax(m);
        if (lane == 0) redm[r * 4 + wave] = m;
    }
    __syncthreads();
    if (tid < 16) {
        float M = fmaxf(fmaxf(redm[tid * 4], redm[tid * 4 + 1]),
                        fmaxf(redm[tid * 4 + 2], redm[tid * 4 + 3]));
        float mm = (1.0f - M) + EPSF;
        float a = 2.0f / mm;
        salpha[tid] = a;
        sbase[tid] = 2.0f - a;
    }
    __syncthreads();

    // pass 2: exp row-sum -> beta
#pragma unroll
    for (int r = 0; r < 16; r++) {
        float a = salpha[r], b = sbase[r];
        float v[16];
        unpack8(d[r][0], v); unpack8(d[r][1], v + 8);
        float s = 0.f;
#pragma unroll
        for (int k = 0; k < 16; k++) s += __expf(fmaf(a, v[k], b));
        s = waveReduceSum(s);
        if (lane == 0) redm[r * 4 + wave] = s;
    }
    __syncthreads();
    if (tid < 16) {
        float S = redm[tid * 4] + redm[tid * 4 + 1] + redm[tid * 4 + 2] + redm[tid * 4 + 3];
        sbeta[tid] = sbase[tid] - __logf(S);
    }
    __syncthreads();

    // pass 3: column logit max over the 16 rows (thread-local in q)
    float cmax[16];
#pragma unroll
    for (int k = 0; k < 16; k++) cmax[k] = -1e30f;
#pragma unroll
    for (int r = 0; r < 16; r++) {
        float a = salpha[r], b = sbeta[r];
        float v[16];
        unpack8(d[r][0], v); unpack8(d[r][1], v + 8);
#pragma unroll
        for (int k = 0; k < 16; k++) cmax[k] = fmaxf(cmax[k], fmaf(a, v[k], b));
    }
    float* outp = partial + ((size_t)(n * 256 + chunk)) * HW + tid * 16;
#pragma unroll
    for (int k = 0; k < 16; k += 4) {
        float4 o = {cmax[k], cmax[k + 1], cmax[k + 2], cmax[k + 3]};
        *(float4*)(outp + k) = o;
    }
}

// ---------- K5a: reduce column partials over 16-chunk groups ----------
__global__ __launch_bounds__(256) void colmax1(const float* __restrict__ partial,
                                               float* __restrict__ partial2) {
    int n = blockIdx.z, grp = blockIdx.y;
    int q = blockIdx.x * 256 + threadIdx.x;
    const float* p = partial + ((size_t)n * 256 + grp * 16) * HW + q;
    float m = -1e30f;
#pragma unroll
    for (int c = 0; c < 16; c++) m = fmaxf(m, p[(size_t)c * HW]);
    partial2[((size_t)n * 16 + grp) * HW + q] = m;
}

// ---------- K5b: final column max, exp, sum over q ----------
__global__ __launch_bounds__(256) void colmax2(const float* __restrict__ partial2,
                                               float* __restrict__ cxsum) {
    int n = blockIdx.y;
    int q = blockIdx.x * 256 + threadIdx.x;
    const float* p = partial2 + (size_t)n * 16 * HW + q;
    float m = -1e30f;
#pragma unroll
    for (int g = 0; g < 16; g++) m = fmaxf(m, p[(size_t)g * HW]);
    float val = __expf(m);
    val = waveReduceSum(val);
    __shared__ float red[4];
    int lane = threadIdx.x & 63, wave = threadIdx.x >> 6;
    if (lane == 0) red[wave] = val;
    __syncthreads();
    if (threadIdx.x == 0)
        atomicAdd(&cxsum[n], red[0] + red[1] + red[2] + red[3]);
}

// ---------- K6: final loss ----------
__global__ void finalize(const float* __restrict__ cxsum, float* __restrict__ out) {
    if (threadIdx.x == 0 && blockIdx.x == 0) {
        float loss = 0.f;
        for (int n = 0; n < NB; n++) {
            float cx = cxsum[n] * (1.0f / 4096.0f);
            loss += -logf(cx + EPSF);
        }
        out[0] = loss * 0.25f;
    }
}

// ---------- launch ----------
extern "C" void kernel_launch(void* const* d_in, const int* in_sizes, int n_in,
                              void* d_out, int out_size, void* d_ws, size_t ws_size,
                              hipStream_t stream) {
    const float* x = (const float*)d_in[0];
    const float* y = (const float*)d_in[1];
    float* out = (float*)d_out;
    char* ws = (char*)d_ws;

    // workspace layout (~146 MiB total; partial aliases Xn/Yn after GEMM)
    float* mu            = (float*)(ws + 0);                   // 1 KiB
    float* cxsum         = (float*)(ws + 1024);                // 16 B
    float* partial2      = (float*)(ws + 4096);                // 1 MiB
    unsigned short* Xn   = (unsigned short*)(ws + 2097152);    // 8 MiB
    unsigned short* Yn   = (unsigned short*)(ws + 10485760);   // 8 MiB
    float* partial       = (float*)(ws + 2097152);             // 16 MiB (alias Xn+Yn)
    unsigned short* Cos  = (unsigned short*)(ws + 18874368);   // 128 MiB

    hipMemsetAsync(cxsum, 0, NB * sizeof(float), stream);

    mu_kernel<<<C, 256, 0, stream>>>(y, mu);
    prep_kernel<<<NROWS / TP, 256, 0, stream>>>(x, y, mu, Xn, Yn);
    gemm_cos<<<dim3(HW / 128, HW / 128, NB), 256, 0, stream>>>(Xn, Yn, Cos);
    rowcol<<<dim3(256, NB), 256, 0, stream>>>(Cos, partial);
    colmax1<<<dim3(16, 16, NB), 256, 0, stream>>>(partial, partial2);
    colmax2<<<dim3(16, NB), 256, 0, stream>>>(partial2, cxsum);
    finalize<<<1, 64, 0, stream>>>(cxsum, out);
}